// Round 1
// baseline (122.136 us; speedup 1.0000x reference)
//
#include <hip/hip_runtime.h>

#define NIMG   16
#define NA     25200
#define NCH    85
#define NCLS   80
#define CAP    2048          // per-image candidate capacity (~236 expected; 2048 is >100 sigma)
#define TOPK_N 300
#define CONF_T 0.25f
#define IOU_T  0.45f

#define CHUNK  128           // anchors staged per block (128*85*4 = 43.5 KB LDS)
#define FBLK   256           // filter kernel block size
#define NBLK   512           // nms kernel block size
#define NWORDS 5             // ceil(300/64)

// ---------------- Stage 1: filter + compact ----------------
__global__ __launch_bounds__(FBLK) void filter_kernel(
    const float* __restrict__ pred, int* __restrict__ cnt,
    unsigned long long* __restrict__ keys)
{
    __shared__ float lds[CHUNK * NCH];

    const int blocks_per_img = (NA + CHUNK - 1) / CHUNK;   // 197
    int img   = blockIdx.x / blocks_per_img;
    int chunk = blockIdx.x % blocks_per_img;
    int a0    = chunk * CHUNK;
    int count = min(CHUNK, NA - a0);                       // 128 or 112; both *85 %4==0

    // coalesced float4 stage: chunk base is 16B-aligned (a0%4==0, img slab %16==0)
    const float4* src = reinterpret_cast<const float4*>(pred + ((size_t)img * NA + a0) * NCH);
    float4* dst = reinterpret_cast<float4*>(lds);
    int nf4 = count * NCH / 4;
    for (int i = threadIdx.x; i < nf4; i += FBLK) dst[i] = src[i];
    __syncthreads();

    int t = threadIdx.x;
    if (t < count) {
        const float* p = &lds[t * NCH];                    // stride 85: bank-conflict-free
        float obj = p[4];
        if (obj > CONF_T) {
            float best = -1.0f; int bestj = -1;
            #pragma unroll 8
            for (int j = 0; j < NCLS; ++j) {
                float s = obj * p[5 + j];                  // same rounding as reference scores
                if (s > best) { best = s; bestj = j; }     // strict >: first-index argmax tie-break
            }
            if (bestj == 0 && best > CONF_T) {
                int pos = atomicAdd(&cnt[img], 1);
                if (pos < CAP) {
                    unsigned cb = __float_as_uint(best);   // conf > 0 so bits are order-preserving
                    unsigned a  = (unsigned)(a0 + t);
                    // key: conf desc, then index asc on ties (matches lax.top_k)
                    keys[(size_t)img * CAP + pos] =
                        ((unsigned long long)cb << 32) | (unsigned long long)(0xFFFFFFFFu - a);
                }
            }
        }
    }
}

// ---------------- Stage 2: sort + NMS + mean ----------------
__global__ __launch_bounds__(NBLK) void nms_kernel(
    const float* __restrict__ pred, const int* __restrict__ cnt,
    const unsigned long long* __restrict__ keys_g, float* __restrict__ out)
{
    __shared__ unsigned long long keys[CAP];
    __shared__ float bx1[TOPK_N], by1[TOPK_N], bx2[TOPK_N], by2[TOPK_N], bconf[TOPK_N];
    __shared__ unsigned long long mask[TOPK_N * NWORDS];
    __shared__ unsigned long long keepw[NWORDS];
    __shared__ float rsum[NBLK / 64];
    __shared__ int   rcnt[NBLK / 64];

    int img = blockIdx.x;
    int tid = threadIdx.x;
    int n = min(cnt[img], CAP);

    // ---- bitonic sort (descending) of N = next_pow2(n) keys ----
    int N = 1; while (N < n) N <<= 1;
    for (int i = tid; i < N; i += NBLK)
        keys[i] = (i < n) ? keys_g[(size_t)img * CAP + i] : 0ULL;
    __syncthreads();
    for (int k = 2; k <= N; k <<= 1) {
        for (int j = k >> 1; j > 0; j >>= 1) {
            for (int i = tid; i < N; i += NBLK) {
                int p = i ^ j;
                if (p > i) {
                    unsigned long long a = keys[i], b = keys[p];
                    bool desc = ((i & k) == 0);
                    if ((a < b) == desc) { keys[i] = b; keys[p] = a; }
                }
            }
            __syncthreads();
        }
    }

    int m = min(n, TOPK_N);

    // ---- gather boxes for the top-m, xywh -> xyxy ----
    if (tid < m) {
        unsigned long long kk = keys[tid];
        unsigned a = 0xFFFFFFFFu - (unsigned)(kk & 0xFFFFFFFFu);
        float conf = __uint_as_float((unsigned)(kk >> 32));
        const float* p = pred + ((size_t)img * NA + a) * NCH;
        float x = p[0], y = p[1], w = p[2], h = p[3];
        bx1[tid] = x - w * 0.5f;
        by1[tid] = y - h * 0.5f;
        bx2[tid] = x + w * 0.5f;
        by2[tid] = y + h * 0.5f;
        bconf[tid] = conf;
    }
    __syncthreads();

    // ---- parallel suppression bit-matrix: word (i,w) covers j in [w*64, w*64+64) ----
    for (int idx = tid; idx < m * NWORDS; idx += NBLK) {
        int i = idx / NWORDS, w = idx % NWORDS;
        unsigned long long bits = 0ULL;
        int jlo = w * 64, jhi = min(jlo + 64, m);
        if (jhi > i + 1) {
            float ax1 = bx1[i], ay1 = by1[i], ax2 = bx2[i], ay2 = by2[i];
            float a1 = (ax2 - ax1) * (ay2 - ay1);
            for (int j = max(jlo, i + 1); j < jhi; ++j) {
                float ltx = fmaxf(ax1, bx1[j]);
                float lty = fmaxf(ay1, by1[j]);
                float rbx = fminf(ax2, bx2[j]);
                float rby = fminf(ay2, by2[j]);
                float ww = fmaxf(rbx - ltx, 0.0f);
                float hh = fmaxf(rby - lty, 0.0f);
                float inter = ww * hh;
                float a2 = (bx2[j] - bx1[j]) * (by2[j] - by1[j]);
                float iou = inter / (a1 + a2 - inter + 1e-9f);  // exact ref op order
                if (iou > IOU_T) bits |= 1ULL << (j - jlo);
            }
        }
        mask[i * NWORDS + w] = bits;
    }
    __syncthreads();

    // ---- serial greedy scan: single wave, bitmask registers, no block syncs ----
    if (tid < 64) {
        int lane = tid;
        unsigned long long kw = 0ULL;
        if (lane < NWORDS) {
            int rem = m - lane * 64;
            kw = (rem >= 64) ? ~0ULL : ((rem <= 0) ? 0ULL : ((1ULL << rem) - 1ULL));
        }
        for (int i = 0; i < m; ++i) {
            unsigned long long wi = __shfl(kw, i >> 6);        // broadcast owner's word
            if ((wi >> (i & 63)) & 1ULL) {                     // keep[i] still alive?
                unsigned long long mw = (lane < NWORDS) ? mask[i * NWORDS + lane] : 0ULL;
                kw &= ~mw;
            }
        }
        if (lane < NWORDS) keepw[lane] = kw;
    }
    __syncthreads();

    // ---- mean of kept confidences ----
    float s = 0.0f; int c = 0;
    if (tid < m) {
        if ((keepw[tid >> 6] >> (tid & 63)) & 1ULL) { s = bconf[tid]; c = 1; }
    }
    for (int off = 32; off > 0; off >>= 1) {
        s += __shfl_down(s, off);
        c += __shfl_down(c, off);
    }
    int wid = tid >> 6;
    if ((tid & 63) == 0) { rsum[wid] = s; rcnt[wid] = c; }
    __syncthreads();
    if (tid == 0) {
        float S = 0.0f; int C = 0;
        for (int wv = 0; wv < NBLK / 64; ++wv) { S += rsum[wv]; C += rcnt[wv]; }
        out[img] = (C > 0) ? S / (float)C : 0.0f;
    }
}

extern "C" void kernel_launch(void* const* d_in, const int* in_sizes, int n_in,
                              void* d_out, int out_size, void* d_ws, size_t ws_size,
                              hipStream_t stream) {
    const float* pred = (const float*)d_in[0];
    float* out = (float*)d_out;

    // ws layout: [0,64)   per-image counters (zeroed each launch)
    //            [256,..) per-image key buffers (16 * 2048 * 8 B = 256 KB)
    int* cnt = (int*)d_ws;
    unsigned long long* keys = (unsigned long long*)((char*)d_ws + 256);

    hipMemsetAsync(d_ws, 0, 256, stream);

    const int blocks_per_img = (NA + CHUNK - 1) / CHUNK;
    filter_kernel<<<NIMG * blocks_per_img, FBLK, 0, stream>>>(pred, cnt, keys);
    nms_kernel<<<NIMG, NBLK, 0, stream>>>(pred, cnt, keys, out);
}